// Round 1
// baseline (208.732 us; speedup 1.0000x reference)
//
#include <hip/hip_runtime.h>
#include <math.h>

#define C_IN   256
#define C_HEAD 32
#define HW     361          // 19*19
#define NTHR   384          // 6 waves
#define CV     48

__global__ __launch_bounds__(NTHR) void vh_fused(
    const float* __restrict__ x,
    const float* __restrict__ conv_w,
    const float* __restrict__ fc1_w, const float* __restrict__ fc1_b,
    const float* __restrict__ fc2_w, const float* __restrict__ fc2_b,
    const float* __restrict__ fc3_w, const float* __restrict__ fc3_b,
    const float* __restrict__ sc_w,  const float* __restrict__ sc_b,
    const float* __restrict__ fc4_w, const float* __restrict__ fc4_b,
    const float* __restrict__ fc5_w, const float* __restrict__ fc5_b,
    float* __restrict__ out, int B)
{
    const int b    = blockIdx.x;
    const int tid  = threadIdx.x;
    const int wave = tid >> 6;
    const int lane = tid & 63;
    const int p    = tid;
    const bool act = (p < HW);
    const int pc   = act ? p : (HW - 1);   // clamp so loop is convergent -> uniform weight s_loads

    __shared__ float lds_sum[C_HEAD][6];
    __shared__ float lds_max[C_HEAD][6];
    __shared__ float vp[3 * C_HEAD];
    __shared__ float base_l[CV], dco_l[CV], f5_l[CV];

    float acc[C_HEAD];
    #pragma unroll
    for (int o = 0; o < C_HEAD; ++o) acc[o] = 0.f;

    const float* __restrict__ xb = x + (size_t)b * C_IN * HW;

    // ---- 1x1 conv: V[b,o,p] = sum_c x[b,c,p] * w[o,c] ----
    #pragma unroll 4
    for (int c = 0; c < C_IN; ++c) {
        float xv = xb[c * HW + pc];
        #pragma unroll
        for (int o = 0; o < C_HEAD; ++o)
            acc[o] = fmaf(xv, conv_w[o * C_IN + c], acc[o]);
    }

    // ---- spatial mean & max reduction ----
    #pragma unroll
    for (int o = 0; o < C_HEAD; ++o) {
        float s = act ? acc[o] : 0.f;
        float m = act ? acc[o] : -3.0e38f;
        #pragma unroll
        for (int off = 32; off > 0; off >>= 1) {
            s += __shfl_xor(s, off, 64);
            m  = fmaxf(m, __shfl_xor(m, off, 64));
        }
        if (lane == 0) { lds_sum[o][wave] = s; lds_max[o][wave] = m; }
    }
    __syncthreads();

    if (tid < C_HEAD) {
        float s = 0.f, m = -3.0e38f;
        #pragma unroll
        for (int w = 0; w < 6; ++w) { s += lds_sum[tid][w]; m = fmaxf(m, lds_max[tid][w]); }
        float mean1 = s * (1.0f / (float)HW);
        vp[tid]              = mean1;
        vp[C_HEAD + tid]     = mean1 * ((19.0f - 9.0f) * 0.1f);
        vp[2 * C_HEAD + tid] = m;
    }
    __syncthreads();

    // ---- heads: wave 0 only ----
    if (wave == 0) {
        const int j = lane;
        float h1 = 0.f, h3 = 0.f;
        if (j < CV) {
            float a1 = fc1_b[j], a3 = fc3_b[j], a4 = fc4_b[j];
            #pragma unroll
            for (int k = 0; k < 96; ++k) {
                float v = vp[k];
                a1 = fmaf(v, fc1_w[j * 96 + k], a1);
                a3 = fmaf(v, fc3_w[j * 96 + k], a3);
                a4 = fmaf(v, fc4_w[j * 97 + k], a4);
            }
            h1 = fmaxf(a1, 0.f) * fc2_w[j];
            h3 = fmaxf(a3, 0.f) * sc_w[j];
            base_l[j] = a4;
            dco_l[j]  = fc4_w[j * 97 + 96];
            f5_l[j]   = fc5_w[j];
        }
        // game outcome + scaling (48-lane dot reductions)
        float s1 = h1, s3 = h3;
        #pragma unroll
        for (int off = 32; off > 0; off >>= 1) {
            s1 += __shfl_xor(s1, off, 64);
            s3 += __shfl_xor(s3, off, 64);
        }
        float game = tanhf(s1 + fc2_b[0]);
        float scal = s3 + sc_b[0];
        if (lane == 0) out[b] = game;

        // distance logits: lane d in [0,41)
        float z = -3.0e38f;
        if (lane < 41) {
            float dval = (float)(lane - 20);
            float lg = fc5_b[0];
            #pragma unroll
            for (int jj = 0; jj < CV; ++jj) {
                float t = fmaf(dval, dco_l[jj], base_l[jj]);
                t = fmaxf(t, 0.f);
                lg = fmaf(t, f5_l[jj], lg);
            }
            z = lg * scal;
        }
        // softmax over 41 lanes
        float mz = z;
        #pragma unroll
        for (int off = 32; off > 0; off >>= 1) mz = fmaxf(mz, __shfl_xor(mz, off, 64));
        float e = (lane < 41) ? expf(z - mz) : 0.f;
        float se = e;
        #pragma unroll
        for (int off = 32; off > 0; off >>= 1) se += __shfl_xor(se, off, 64);
        if (lane < 41) out[B + b * 41 + lane] = e / se;
    }
}

extern "C" void kernel_launch(void* const* d_in, const int* in_sizes, int n_in,
                              void* d_out, int out_size, void* d_ws, size_t ws_size,
                              hipStream_t stream) {
    const float* x      = (const float*)d_in[0];
    const float* conv_w = (const float*)d_in[1];
    const float* fc1_w  = (const float*)d_in[2];
    const float* fc1_b  = (const float*)d_in[3];
    const float* fc2_w  = (const float*)d_in[4];
    const float* fc2_b  = (const float*)d_in[5];
    const float* fc3_w  = (const float*)d_in[6];
    const float* fc3_b  = (const float*)d_in[7];
    const float* sc_w   = (const float*)d_in[8];
    const float* sc_b   = (const float*)d_in[9];
    const float* fc4_w  = (const float*)d_in[10];
    const float* fc4_b  = (const float*)d_in[11];
    const float* fc5_w  = (const float*)d_in[12];
    const float* fc5_b  = (const float*)d_in[13];
    float* out = (float*)d_out;

    int B = in_sizes[0] / (C_IN * HW);

    vh_fused<<<dim3(B), dim3(NTHR), 0, stream>>>(
        x, conv_w, fc1_w, fc1_b, fc2_w, fc2_b, fc3_w, fc3_b,
        sc_w, sc_b, fc4_w, fc4_b, fc5_w, fc5_b, out, B);
}